// Round 5
// baseline (365.686 us; speedup 1.0000x reference)
//
#include <hip/hip_runtime.h>
#include <hip/hip_bf16.h>

#define IN_CH 128
#define OUT_CH 64

// ---------------- degree count (int4-vectorized) ----------------
__global__ void __launch_bounds__(256) count_kernel(const int* __restrict__ col,
                                                    int* __restrict__ cnt, int E) {
    int t = blockIdx.x * blockDim.x + threadIdx.x;
    int base = t * 4;
    if (base + 3 < E) {
        int4 c = *(const int4*)(col + base);
        atomicAdd(&cnt[c.x], 1);
        atomicAdd(&cnt[c.y], 1);
        atomicAdd(&cnt[c.z], 1);
        atomicAdd(&cnt[c.w], 1);
    } else {
        for (int i = base; i < E; ++i) atomicAdd(&cnt[col[i]], 1);
    }
}

// ---------------- 3-phase parallel exclusive scan ----------------
__global__ void __launch_bounds__(256) partial_kernel(const int* __restrict__ cnt,
                                                      int* __restrict__ bsum, int n) {
    __shared__ int red[256];
    int tid = threadIdx.x;
    int i = blockIdx.x * 256 + tid;
    red[tid] = (i < n) ? cnt[i] : 0;
    __syncthreads();
    for (int d = 128; d > 0; d >>= 1) {
        if (tid < d) red[tid] += red[tid + d];
        __syncthreads();
    }
    if (tid == 0) bsum[blockIdx.x] = red[0];
}

__global__ void __launch_bounds__(256) scansums_kernel(int* __restrict__ bsum, int nb) {
    __shared__ int ps[256];
    int tid = threadIdx.x;
    int v = (tid < nb) ? bsum[tid] : 0;
    ps[tid] = v;
    __syncthreads();
    for (int d = 1; d < 256; d <<= 1) {
        int t = 0;
        if (tid >= d) t = ps[tid - d];
        __syncthreads();
        if (tid >= d) ps[tid] += t;
        __syncthreads();
    }
    if (tid < nb) bsum[tid] = ps[tid] - v;   // exclusive
}

__global__ void __launch_bounds__(256) scanwrite_kernel(const int* __restrict__ cnt,
                                                        const int* __restrict__ bsum,
                                                        int* __restrict__ off,
                                                        int* __restrict__ pos,
                                                        float* __restrict__ dis, int n) {
    __shared__ int ps[256];
    int tid = threadIdx.x;
    int i = blockIdx.x * 256 + tid;
    int c = (i < n) ? cnt[i] : 0;
    ps[tid] = c;
    __syncthreads();
    for (int d = 1; d < 256; d <<= 1) {
        int t = 0;
        if (tid >= d) t = ps[tid - d];
        __syncthreads();
        if (tid >= d) ps[tid] += t;
        __syncthreads();
    }
    int excl = ps[tid] - c + bsum[blockIdx.x];
    if (i < n) {
        off[i] = excl;
        pos[i] = excl;
        dis[i] = rsqrtf((float)(c + 1));   // +1 self-loop, matches gcn_norm
        if (i == n - 1) off[n] = excl + c;
    }
}

// ---------------- scatter: CSR edge list as ushort source indices ----------------
// Norm is folded into node features (z = dis * y), so the edge record is just
// the source index; N < 65536 -> 2 bytes. 1.6 MB target fits each XCD L2 ->
// random stores coalesce in L2 instead of thrashing write-allocate lines.
__global__ void __launch_bounds__(256) scatter_kernel(const int* __restrict__ row,
                                                      const int* __restrict__ col,
                                                      int* __restrict__ pos,
                                                      unsigned short* __restrict__ eidx,
                                                      int E) {
    int t = blockIdx.x * blockDim.x + threadIdx.x;
    int base = t * 2;
    if (base + 1 < E) {
        int2 r = *(const int2*)(row + base);
        int2 c = *(const int2*)(col + base);
        int p0 = atomicAdd(&pos[c.x], 1);
        eidx[p0] = (unsigned short)r.x;
        int p1 = atomicAdd(&pos[c.y], 1);
        eidx[p1] = (unsigned short)r.y;
    } else if (base < E) {
        int r = row[base], c = col[base];
        int p = atomicAdd(&pos[c], 1);
        eidx[p] = (unsigned short)r;
    }
}

// ---------------- z = dis * (X @ W^T) : lane = node, acc in VGPRs, W via s_load ----------------
// One thread per node. acc[64] + two 4xfloat4 x buffers ~ 110 VGPRs; (256,1)
// stops the allocator from spilling. W addresses are wave-uniform -> scalar
// loads (32 KB, K$/L2-hot, reused by every wave); FMA = v_fma(vacc, vx, s_w).
__global__ void __launch_bounds__(256, 1) gemm_kernel(const float* __restrict__ x,
                                                      const float* __restrict__ W,
                                                      const float* __restrict__ dis,
                                                      float* __restrict__ z, int n) {
    int v = blockIdx.x * 256 + threadIdx.x;
    if (v >= n) return;
    float acc[OUT_CH];
#pragma unroll
    for (int o = 0; o < OUT_CH; ++o) acc[o] = 0.f;
    const float4* xr = (const float4*)(x + (size_t)v * IN_CH);
    float4 xv0 = xr[0], xv1 = xr[1], xv2 = xr[2], xv3 = xr[3];
#pragma unroll 1
    for (int kc = 0; kc < IN_CH / 16; ++kc) {
        int kn = (kc + 1 < IN_CH / 16) ? kc + 1 : kc;   // clamp: no OOB on last row
        float4 xn0 = xr[kn * 4 + 0], xn1 = xr[kn * 4 + 1];
        float4 xn2 = xr[kn * 4 + 2], xn3 = xr[kn * 4 + 3];
#pragma unroll
        for (int o = 0; o < OUT_CH; ++o) {
            const float4* Wo = (const float4*)(W + o * IN_CH + kc * 16);
            float4 w0 = Wo[0], w1 = Wo[1], w2 = Wo[2], w3 = Wo[3];   // uniform -> s_load
            float s;
            s = fmaf(xv0.x, w0.x, acc[o]); s = fmaf(xv0.y, w0.y, s);
            s = fmaf(xv0.z, w0.z, s);      s = fmaf(xv0.w, w0.w, s);
            s = fmaf(xv1.x, w1.x, s);      s = fmaf(xv1.y, w1.y, s);
            s = fmaf(xv1.z, w1.z, s);      s = fmaf(xv1.w, w1.w, s);
            s = fmaf(xv2.x, w2.x, s);      s = fmaf(xv2.y, w2.y, s);
            s = fmaf(xv2.z, w2.z, s);      s = fmaf(xv2.w, w2.w, s);
            s = fmaf(xv3.x, w3.x, s);      s = fmaf(xv3.y, w3.y, s);
            s = fmaf(xv3.z, w3.z, s);      s = fmaf(xv3.w, w3.w, s);
            acc[o] = s;
        }
        xv0 = xn0; xv1 = xn1; xv2 = xn2; xv3 = xn3;
    }
    float dv = dis[v];
    float4* zr = (float4*)(z + (size_t)v * OUT_CH);
#pragma unroll
    for (int o = 0; o < OUT_CH / 4; ++o)
        zr[o] = make_float4(dv * acc[4 * o], dv * acc[4 * o + 1],
                            dv * acc[4 * o + 2], dv * acc[4 * o + 3]);
}

// ---------------- propagation hop: wave per node, 4 edges x float4 per issue ----------------
// t[v] = zin[v] + sum_{edges} zin[row];  MODE 0: out = dis^2 * t (next z)
//                                        MODE 1: out = dis * t + bias (final)
template <int MODE>
__global__ void __launch_bounds__(256) hop_kernel(const float* __restrict__ zin,
                                                  float* __restrict__ out,
                                                  const unsigned short* __restrict__ eidx,
                                                  const int* __restrict__ off,
                                                  const float* __restrict__ dis,
                                                  const float* __restrict__ bias, int n) {
    int v = (int)((blockIdx.x * 256 + threadIdx.x) >> 6);
    if (v >= n) return;
    int lane = threadIdx.x & 63;
    int grp = lane >> 4;       // which edge within a quad
    int sub = lane & 15;       // which float4 chunk of the 64-float row
    int s = off[v], e = off[v + 1];
    float4 acc = make_float4(0.f, 0.f, 0.f, 0.f);
    if (grp == 0) {            // self-loop term (z already carries dis scaling)
        acc = ((const float4*)(zin + (size_t)v * OUT_CH))[sub];
    }
    int i = s + grp;
    bool have = (i < e);
    int r = have ? (int)eidx[i] : 0;
    while (have) {
        int j = i + 4;
        bool hnext = (j < e);
        int rn = hnext ? (int)eidx[j] : 0;   // prefetch next descriptor
        float4 t = ((const float4*)(zin + (size_t)r * OUT_CH))[sub];
        acc.x += t.x; acc.y += t.y; acc.z += t.z; acc.w += t.w;
        r = rn; i = j; have = hnext;
    }
    // reduce the 4 edge slots: lanes {sub, sub+16, sub+32, sub+48}
    acc.x += __shfl_xor(acc.x, 16, 64); acc.x += __shfl_xor(acc.x, 32, 64);
    acc.y += __shfl_xor(acc.y, 16, 64); acc.y += __shfl_xor(acc.y, 32, 64);
    acc.z += __shfl_xor(acc.z, 16, 64); acc.z += __shfl_xor(acc.z, 32, 64);
    acc.w += __shfl_xor(acc.w, 16, 64); acc.w += __shfl_xor(acc.w, 32, 64);
    if (grp == 0) {
        float dv = dis[v];
        float sc = (MODE == 0) ? dv * dv : dv;
        float4 o4 = make_float4(sc * acc.x, sc * acc.y, sc * acc.z, sc * acc.w);
        if (MODE == 1) {
            float4 bb = ((const float4*)bias)[sub];
            o4.x += bb.x; o4.y += bb.y; o4.z += bb.z; o4.w += bb.w;
        }
        ((float4*)(out + (size_t)v * OUT_CH))[sub] = o4;
    }
}

extern "C" void kernel_launch(void* const* d_in, const int* in_sizes, int n_in,
                              void* d_out, int out_size, void* d_ws, size_t ws_size,
                              hipStream_t stream) {
    const float* x = (const float*)d_in[0];
    const int* ei = (const int*)d_in[1];
    const float* W = (const float*)d_in[2];
    const float* b = (const float*)d_in[3];
    int n = in_sizes[0] / IN_CH;   // 50000
    int E = in_sizes[1] / 2;       // 800000
    const int* row = ei;           // edge_index[0] = source
    const int* col = ei + E;       // edge_index[1] = target

    char* ws = (char*)d_ws;
    size_t o = 0;
    auto alloc = [&](size_t bytes) -> void* {
        void* p = ws + o;
        o += (bytes + 255) & ~(size_t)255;
        return p;
    };
    int*            cnt  = (int*)alloc((size_t)n * 4);
    int*            off  = (int*)alloc((size_t)(n + 1) * 4);
    int*            pos  = (int*)alloc((size_t)n * 4);
    float*          dis  = (float*)alloc((size_t)n * 4);
    unsigned short* eidx = (unsigned short*)alloc((size_t)E * 2);
    float*          zA   = (float*)alloc((size_t)n * OUT_CH * 4);
    float*          zB   = (float*)alloc((size_t)n * OUT_CH * 4);
    int*            bsum = (int*)alloc(1024 * 4);

    int nTiles = (n + 255) / 256;  // 196

    hipMemsetAsync(cnt, 0, (size_t)n * 4, stream);
    count_kernel<<<((E + 3) / 4 + 255) / 256, 256, 0, stream>>>(col, cnt, E);
    partial_kernel<<<nTiles, 256, 0, stream>>>(cnt, bsum, n);
    scansums_kernel<<<1, 256, 0, stream>>>(bsum, nTiles);
    scanwrite_kernel<<<nTiles, 256, 0, stream>>>(cnt, bsum, off, pos, dis, n);
    scatter_kernel<<<((E + 1) / 2 + 255) / 256, 256, 0, stream>>>(row, col, pos, eidx, E);
    gemm_kernel<<<nTiles, 256, 0, stream>>>(x, W, dis, zA, n);
    int hopBlocks = (n + 3) / 4;   // wave per node
    hop_kernel<0><<<hopBlocks, 256, 0, stream>>>(zA, zB, eidx, off, dis, nullptr, n);
    hop_kernel<1><<<hopBlocks, 256, 0, stream>>>(zB, (float*)d_out, eidx, off, dis, b, n);
}

// Round 6
// 249.925 us; speedup vs baseline: 1.4632x; 1.4632x over previous
//
#include <hip/hip_runtime.h>
#include <hip/hip_bf16.h>

#define IN_CH 128
#define OUT_CH 64

// ---------------- degree count (int4-vectorized) ----------------
__global__ void __launch_bounds__(256) count_kernel(const int* __restrict__ col,
                                                    int* __restrict__ cnt, int E) {
    int t = blockIdx.x * blockDim.x + threadIdx.x;
    int base = t * 4;
    if (base + 3 < E) {
        int4 c = *(const int4*)(col + base);
        atomicAdd(&cnt[c.x], 1);
        atomicAdd(&cnt[c.y], 1);
        atomicAdd(&cnt[c.z], 1);
        atomicAdd(&cnt[c.w], 1);
    } else {
        for (int i = base; i < E; ++i) atomicAdd(&cnt[col[i]], 1);
    }
}

// ---------------- 3-phase parallel exclusive scan ----------------
__global__ void __launch_bounds__(256) partial_kernel(const int* __restrict__ cnt,
                                                      int* __restrict__ bsum, int n) {
    __shared__ int red[256];
    int tid = threadIdx.x;
    int i = blockIdx.x * 256 + tid;
    red[tid] = (i < n) ? cnt[i] : 0;
    __syncthreads();
    for (int d = 128; d > 0; d >>= 1) {
        if (tid < d) red[tid] += red[tid + d];
        __syncthreads();
    }
    if (tid == 0) bsum[blockIdx.x] = red[0];
}

__global__ void __launch_bounds__(256) scansums_kernel(int* __restrict__ bsum, int nb) {
    __shared__ int ps[256];
    int tid = threadIdx.x;
    int v = (tid < nb) ? bsum[tid] : 0;
    ps[tid] = v;
    __syncthreads();
    for (int d = 1; d < 256; d <<= 1) {
        int t = 0;
        if (tid >= d) t = ps[tid - d];
        __syncthreads();
        if (tid >= d) ps[tid] += t;
        __syncthreads();
    }
    if (tid < nb) bsum[tid] = ps[tid] - v;   // exclusive
}

__global__ void __launch_bounds__(256) scanwrite_kernel(const int* __restrict__ cnt,
                                                        const int* __restrict__ bsum,
                                                        int* __restrict__ off,
                                                        int* __restrict__ pos,
                                                        float* __restrict__ dis, int n) {
    __shared__ int ps[256];
    int tid = threadIdx.x;
    int i = blockIdx.x * 256 + tid;
    int c = (i < n) ? cnt[i] : 0;
    ps[tid] = c;
    __syncthreads();
    for (int d = 1; d < 256; d <<= 1) {
        int t = 0;
        if (tid >= d) t = ps[tid - d];
        __syncthreads();
        if (tid >= d) ps[tid] += t;
        __syncthreads();
    }
    int excl = ps[tid] - c + bsum[blockIdx.x];
    if (i < n) {
        off[i] = excl;
        pos[i] = excl;
        dis[i] = rsqrtf((float)(c + 1));   // +1 self-loop, matches gcn_norm
        if (i == n - 1) off[n] = excl + c;
    }
}

// ---------------- scatter: CSR edge list as ushort source indices ----------------
__global__ void __launch_bounds__(256) scatter_kernel(const int* __restrict__ row,
                                                      const int* __restrict__ col,
                                                      int* __restrict__ pos,
                                                      unsigned short* __restrict__ eidx,
                                                      int E) {
    int t = blockIdx.x * blockDim.x + threadIdx.x;
    int base = t * 2;
    if (base + 1 < E) {
        int2 r = *(const int2*)(row + base);
        int2 c = *(const int2*)(col + base);
        int p0 = atomicAdd(&pos[c.x], 1);
        eidx[p0] = (unsigned short)r.x;
        int p1 = atomicAdd(&pos[c.y], 1);
        eidx[p1] = (unsigned short)r.y;
    } else if (base < E) {
        int r = row[base], c = col[base];
        int p = atomicAdd(&pos[c], 1);
        eidx[p] = (unsigned short)r;
    }
}

// ---------------- z = dis * (X @ W^T) : register-tiled LDS GEMM ----------------
// Block: 256 threads -> 64 nodes x 64 outputs, K=128 staged in LDS.
// Thread (tx=t&15, ty=t>>4) computes 4 nodes (tx+16i) x 4 outputs (ty*4+j),
// acc[4][4] = 16 VGPRs (no spill). Per k-quad: 8 ds_read_b128 (broadcast /
// 2-way = free) vs 64 v_fma -> VALU-bound. Pad 132 keeps 16B alignment.
__global__ void __launch_bounds__(256, 2) gemm_kernel(const float* __restrict__ x,
                                                      const float* __restrict__ W,
                                                      const float* __restrict__ dis,
                                                      float* __restrict__ z, int n) {
    __shared__ float Xs[64 * 132];
    __shared__ float Ws[64 * 132];
    int t = threadIdx.x;
    int m0 = blockIdx.x * 64;
#pragma unroll
    for (int r = 0; r < 8; ++r) {               // stage W: 64x128 = 2048 float4
        int f = t + 256 * r;
        int o = f >> 5, kq = f & 31;
        float4 w = ((const float4*)W)[f];
        *(float4*)&Ws[o * 132 + kq * 4] = w;
    }
#pragma unroll
    for (int r = 0; r < 8; ++r) {               // stage X tile (clamped tail)
        int f = t + 256 * r;
        int node = f >> 5, kq = f & 31;
        int gv = min(m0 + node, n - 1);
        float4 xv = ((const float4*)(x + (size_t)gv * IN_CH))[kq];
        *(float4*)&Xs[node * 132 + kq * 4] = xv;
    }
    __syncthreads();
    int tx = t & 15, ty = t >> 4;
    float acc[4][4];
#pragma unroll
    for (int i = 0; i < 4; ++i)
#pragma unroll
        for (int j = 0; j < 4; ++j) acc[i][j] = 0.f;

#pragma unroll 4
    for (int kq = 0; kq < 32; ++kq) {
        float4 xa[4], wb[4];
#pragma unroll
        for (int i = 0; i < 4; ++i) xa[i] = *(const float4*)&Xs[(tx + 16 * i) * 132 + kq * 4];
#pragma unroll
        for (int j = 0; j < 4; ++j) wb[j] = *(const float4*)&Ws[(ty * 4 + j) * 132 + kq * 4];
#pragma unroll
        for (int i = 0; i < 4; ++i)
#pragma unroll
            for (int j = 0; j < 4; ++j) {
                float s = acc[i][j];
                s = fmaf(xa[i].x, wb[j].x, s);
                s = fmaf(xa[i].y, wb[j].y, s);
                s = fmaf(xa[i].z, wb[j].z, s);
                s = fmaf(xa[i].w, wb[j].w, s);
                acc[i][j] = s;
            }
    }
#pragma unroll
    for (int i = 0; i < 4; ++i) {
        int v = m0 + tx + 16 * i;
        if (v < n) {
            float dv = dis[v];
            float4 o4 = make_float4(dv * acc[i][0], dv * acc[i][1],
                                    dv * acc[i][2], dv * acc[i][3]);
            *(float4*)&z[(size_t)v * OUT_CH + ty * 4] = o4;
        }
    }
}

// ---------------- propagation hop: wave per node, 4 edges x float4 per issue ----------------
// t[v] = zin[v] + sum_{edges} zin[row];  MODE 0: out = dis^2 * t (next z)
//                                        MODE 1: out = dis * t + bias (final)
template <int MODE>
__global__ void __launch_bounds__(256) hop_kernel(const float* __restrict__ zin,
                                                  float* __restrict__ out,
                                                  const unsigned short* __restrict__ eidx,
                                                  const int* __restrict__ off,
                                                  const float* __restrict__ dis,
                                                  const float* __restrict__ bias, int n) {
    int v = (int)((blockIdx.x * 256 + threadIdx.x) >> 6);
    if (v >= n) return;
    int lane = threadIdx.x & 63;
    int grp = lane >> 4;       // which edge within a quad
    int sub = lane & 15;       // which float4 chunk of the 64-float row
    int s = off[v], e = off[v + 1];
    float4 acc = make_float4(0.f, 0.f, 0.f, 0.f);
    if (grp == 0) {            // self-loop term (z already carries dis scaling)
        acc = ((const float4*)(zin + (size_t)v * OUT_CH))[sub];
    }
    int i = s + grp;
    bool have = (i < e);
    int r = have ? (int)eidx[i] : 0;
    while (have) {
        int j = i + 4;
        bool hnext = (j < e);
        int rn = hnext ? (int)eidx[j] : 0;   // prefetch next descriptor
        float4 t = ((const float4*)(zin + (size_t)r * OUT_CH))[sub];
        acc.x += t.x; acc.y += t.y; acc.z += t.z; acc.w += t.w;
        r = rn; i = j; have = hnext;
    }
    // reduce the 4 edge slots: lanes {sub, sub+16, sub+32, sub+48}
    acc.x += __shfl_xor(acc.x, 16, 64); acc.x += __shfl_xor(acc.x, 32, 64);
    acc.y += __shfl_xor(acc.y, 16, 64); acc.y += __shfl_xor(acc.y, 32, 64);
    acc.z += __shfl_xor(acc.z, 16, 64); acc.z += __shfl_xor(acc.z, 32, 64);
    acc.w += __shfl_xor(acc.w, 16, 64); acc.w += __shfl_xor(acc.w, 32, 64);
    if (grp == 0) {
        float dv = dis[v];
        float sc = (MODE == 0) ? dv * dv : dv;
        float4 o4 = make_float4(sc * acc.x, sc * acc.y, sc * acc.z, sc * acc.w);
        if (MODE == 1) {
            float4 bb = ((const float4*)bias)[sub];
            o4.x += bb.x; o4.y += bb.y; o4.z += bb.z; o4.w += bb.w;
        }
        ((float4*)(out + (size_t)v * OUT_CH))[sub] = o4;
    }
}

extern "C" void kernel_launch(void* const* d_in, const int* in_sizes, int n_in,
                              void* d_out, int out_size, void* d_ws, size_t ws_size,
                              hipStream_t stream) {
    const float* x = (const float*)d_in[0];
    const int* ei = (const int*)d_in[1];
    const float* W = (const float*)d_in[2];
    const float* b = (const float*)d_in[3];
    int n = in_sizes[0] / IN_CH;   // 50000
    int E = in_sizes[1] / 2;       // 800000
    const int* row = ei;           // edge_index[0] = source
    const int* col = ei + E;       // edge_index[1] = target

    char* ws = (char*)d_ws;
    size_t o = 0;
    auto alloc = [&](size_t bytes) -> void* {
        void* p = ws + o;
        o += (bytes + 255) & ~(size_t)255;
        return p;
    };
    int*            cnt  = (int*)alloc((size_t)n * 4);
    int*            off  = (int*)alloc((size_t)(n + 1) * 4);
    int*            pos  = (int*)alloc((size_t)n * 4);
    float*          dis  = (float*)alloc((size_t)n * 4);
    unsigned short* eidx = (unsigned short*)alloc((size_t)E * 2);
    float*          zA   = (float*)alloc((size_t)n * OUT_CH * 4);
    float*          zB   = (float*)alloc((size_t)n * OUT_CH * 4);
    int*            bsum = (int*)alloc(1024 * 4);

    int nTiles = (n + 255) / 256;  // 196

    hipMemsetAsync(cnt, 0, (size_t)n * 4, stream);
    count_kernel<<<((E + 3) / 4 + 255) / 256, 256, 0, stream>>>(col, cnt, E);
    partial_kernel<<<nTiles, 256, 0, stream>>>(cnt, bsum, n);
    scansums_kernel<<<1, 256, 0, stream>>>(bsum, nTiles);
    scanwrite_kernel<<<nTiles, 256, 0, stream>>>(cnt, bsum, off, pos, dis, n);
    scatter_kernel<<<((E + 1) / 2 + 255) / 256, 256, 0, stream>>>(row, col, pos, eidx, E);
    gemm_kernel<<<(n + 63) / 64, 256, 0, stream>>>(x, W, dis, zA, n);
    int hopBlocks = (n + 3) / 4;   // wave per node
    hop_kernel<0><<<hopBlocks, 256, 0, stream>>>(zA, zB, eidx, off, dis, nullptr, n);
    hop_kernel<1><<<hopBlocks, 256, 0, stream>>>(zB, (float*)d_out, eidx, off, dis, b, n);
}

// Round 7
// 248.199 us; speedup vs baseline: 1.4734x; 1.0070x over previous
//
#include <hip/hip_runtime.h>
#include <hip/hip_bf16.h>

#define IN_CH 128
#define OUT_CH 64

// ---------------- degree count (int4-vectorized) ----------------
__global__ void __launch_bounds__(256) count_kernel(const int* __restrict__ col,
                                                    int* __restrict__ cnt, int E) {
    int t = blockIdx.x * blockDim.x + threadIdx.x;
    int base = t * 4;
    if (base + 3 < E) {
        int4 c = *(const int4*)(col + base);
        atomicAdd(&cnt[c.x], 1);
        atomicAdd(&cnt[c.y], 1);
        atomicAdd(&cnt[c.z], 1);
        atomicAdd(&cnt[c.w], 1);
    } else {
        for (int i = base; i < E; ++i) atomicAdd(&cnt[col[i]], 1);
    }
}

// ---------------- 3-phase parallel exclusive scan ----------------
__global__ void __launch_bounds__(256) partial_kernel(const int* __restrict__ cnt,
                                                      int* __restrict__ bsum, int n) {
    __shared__ int red[256];
    int tid = threadIdx.x;
    int i = blockIdx.x * 256 + tid;
    red[tid] = (i < n) ? cnt[i] : 0;
    __syncthreads();
    for (int d = 128; d > 0; d >>= 1) {
        if (tid < d) red[tid] += red[tid + d];
        __syncthreads();
    }
    if (tid == 0) bsum[blockIdx.x] = red[0];
}

__global__ void __launch_bounds__(256) scansums_kernel(int* __restrict__ bsum, int nb) {
    __shared__ int ps[256];
    int tid = threadIdx.x;
    int v = (tid < nb) ? bsum[tid] : 0;
    ps[tid] = v;
    __syncthreads();
    for (int d = 1; d < 256; d <<= 1) {
        int t = 0;
        if (tid >= d) t = ps[tid - d];
        __syncthreads();
        if (tid >= d) ps[tid] += t;
        __syncthreads();
    }
    if (tid < nb) bsum[tid] = ps[tid] - v;   // exclusive
}

__global__ void __launch_bounds__(256) scanwrite_kernel(const int* __restrict__ cnt,
                                                        const int* __restrict__ bsum,
                                                        int* __restrict__ off,
                                                        int* __restrict__ pos,
                                                        float* __restrict__ dis, int n) {
    __shared__ int ps[256];
    int tid = threadIdx.x;
    int i = blockIdx.x * 256 + tid;
    int c = (i < n) ? cnt[i] : 0;
    ps[tid] = c;
    __syncthreads();
    for (int d = 1; d < 256; d <<= 1) {
        int t = 0;
        if (tid >= d) t = ps[tid - d];
        __syncthreads();
        if (tid >= d) ps[tid] += t;
        __syncthreads();
    }
    int excl = ps[tid] - c + bsum[blockIdx.x];
    if (i < n) {
        off[i] = excl;
        pos[i] = excl;
        dis[i] = rsqrtf((float)(c + 1));   // +1 self-loop, matches gcn_norm
        if (i == n - 1) off[n] = excl + c;
    }
}

// ---------------- scatter: XCD-partitioned CSR build ----------------
// Random 2B stores from all 8 XCDs fragment each 64B line across 8 private,
// non-coherent L2s -> ~40 MB dirty-sector writebacks for a 1.6 MB array.
// Fix: group g = blockIdx&7 handles only targets in slice g of the node range;
// with round-robin block->XCD dispatch, every eidx line is written by ONE XCD,
// assembles fully in its L2, and writes back once. Each group re-scans the
// whole edge stream (8x reads, L2-cached streaming - cheap). Correct for any
// block->XCD mapping: each edge claimed by exactly one group.
__global__ void __launch_bounds__(256) scatter_kernel(const int* __restrict__ row,
                                                      const int* __restrict__ col,
                                                      int* __restrict__ pos,
                                                      unsigned short* __restrict__ eidx,
                                                      int E, int n) {
    int g = blockIdx.x & 7;
    int bg = blockIdx.x >> 3;
    int bpg = gridDim.x >> 3;
    int lo = (int)(((long long)n * g) >> 3);
    int hi = (int)(((long long)n * (g + 1)) >> 3);
    int t = bg * 256 + threadIdx.x;
    int stride4 = bpg * 256 * 4;
    for (int base = t * 4; base < E; base += stride4) {
        if (base + 3 < E) {
            int4 c = *(const int4*)(col + base);
            int4 r = *(const int4*)(row + base);
            if (c.x >= lo && c.x < hi) { int p = atomicAdd(&pos[c.x], 1); eidx[p] = (unsigned short)r.x; }
            if (c.y >= lo && c.y < hi) { int p = atomicAdd(&pos[c.y], 1); eidx[p] = (unsigned short)r.y; }
            if (c.z >= lo && c.z < hi) { int p = atomicAdd(&pos[c.z], 1); eidx[p] = (unsigned short)r.z; }
            if (c.w >= lo && c.w < hi) { int p = atomicAdd(&pos[c.w], 1); eidx[p] = (unsigned short)r.w; }
        } else {
            for (int i = base; i < E; ++i) {
                int c = col[i];
                if (c >= lo && c < hi) { int p = atomicAdd(&pos[c], 1); eidx[p] = (unsigned short)row[i]; }
            }
        }
    }
}

// ---------------- z = dis * (X @ W^T) : register-tiled LDS GEMM ----------------
__global__ void __launch_bounds__(256, 2) gemm_kernel(const float* __restrict__ x,
                                                      const float* __restrict__ W,
                                                      const float* __restrict__ dis,
                                                      float* __restrict__ z, int n) {
    __shared__ float Xs[64 * 132];
    __shared__ float Ws[64 * 132];
    int t = threadIdx.x;
    int m0 = blockIdx.x * 64;
#pragma unroll
    for (int r = 0; r < 8; ++r) {               // stage W: 64x128 = 2048 float4
        int f = t + 256 * r;
        int o = f >> 5, kq = f & 31;
        float4 w = ((const float4*)W)[f];
        *(float4*)&Ws[o * 132 + kq * 4] = w;
    }
#pragma unroll
    for (int r = 0; r < 8; ++r) {               // stage X tile (clamped tail)
        int f = t + 256 * r;
        int node = f >> 5, kq = f & 31;
        int gv = min(m0 + node, n - 1);
        float4 xv = ((const float4*)(x + (size_t)gv * IN_CH))[kq];
        *(float4*)&Xs[node * 132 + kq * 4] = xv;
    }
    __syncthreads();
    int tx = t & 15, ty = t >> 4;
    float acc[4][4];
#pragma unroll
    for (int i = 0; i < 4; ++i)
#pragma unroll
        for (int j = 0; j < 4; ++j) acc[i][j] = 0.f;

#pragma unroll 4
    for (int kq = 0; kq < 32; ++kq) {
        float4 xa[4], wb[4];
#pragma unroll
        for (int i = 0; i < 4; ++i) xa[i] = *(const float4*)&Xs[(tx + 16 * i) * 132 + kq * 4];
#pragma unroll
        for (int j = 0; j < 4; ++j) wb[j] = *(const float4*)&Ws[(ty * 4 + j) * 132 + kq * 4];
#pragma unroll
        for (int i = 0; i < 4; ++i)
#pragma unroll
            for (int j = 0; j < 4; ++j) {
                float s = acc[i][j];
                s = fmaf(xa[i].x, wb[j].x, s);
                s = fmaf(xa[i].y, wb[j].y, s);
                s = fmaf(xa[i].z, wb[j].z, s);
                s = fmaf(xa[i].w, wb[j].w, s);
                acc[i][j] = s;
            }
    }
#pragma unroll
    for (int i = 0; i < 4; ++i) {
        int v = m0 + tx + 16 * i;
        if (v < n) {
            float dv = dis[v];
            float4 o4 = make_float4(dv * acc[i][0], dv * acc[i][1],
                                    dv * acc[i][2], dv * acc[i][3]);
            *(float4*)&z[(size_t)v * OUT_CH + ty * 4] = o4;
        }
    }
}

// ---------------- propagation hop: wave per node, 4 edges x float4 per issue ----------------
// t[v] = zin[v] + sum_{edges} zin[row];  MODE 0: out = dis^2 * t (next z)
//                                        MODE 1: out = dis * t + bias (final)
template <int MODE>
__global__ void __launch_bounds__(256) hop_kernel(const float* __restrict__ zin,
                                                  float* __restrict__ out,
                                                  const unsigned short* __restrict__ eidx,
                                                  const int* __restrict__ off,
                                                  const float* __restrict__ dis,
                                                  const float* __restrict__ bias, int n) {
    int v = (int)((blockIdx.x * 256 + threadIdx.x) >> 6);
    if (v >= n) return;
    int lane = threadIdx.x & 63;
    int grp = lane >> 4;       // which edge within a quad
    int sub = lane & 15;       // which float4 chunk of the 64-float row
    int s = off[v], e = off[v + 1];
    float4 acc = make_float4(0.f, 0.f, 0.f, 0.f);
    if (grp == 0) {            // self-loop term (z already carries dis scaling)
        acc = ((const float4*)(zin + (size_t)v * OUT_CH))[sub];
    }
    int i = s + grp;
    bool have = (i < e);
    int r = have ? (int)eidx[i] : 0;
    while (have) {
        int j = i + 4;
        bool hnext = (j < e);
        int rn = hnext ? (int)eidx[j] : 0;   // prefetch next descriptor
        float4 t = ((const float4*)(zin + (size_t)r * OUT_CH))[sub];
        acc.x += t.x; acc.y += t.y; acc.z += t.z; acc.w += t.w;
        r = rn; i = j; have = hnext;
    }
    // reduce the 4 edge slots: lanes {sub, sub+16, sub+32, sub+48}
    acc.x += __shfl_xor(acc.x, 16, 64); acc.x += __shfl_xor(acc.x, 32, 64);
    acc.y += __shfl_xor(acc.y, 16, 64); acc.y += __shfl_xor(acc.y, 32, 64);
    acc.z += __shfl_xor(acc.z, 16, 64); acc.z += __shfl_xor(acc.z, 32, 64);
    acc.w += __shfl_xor(acc.w, 16, 64); acc.w += __shfl_xor(acc.w, 32, 64);
    if (grp == 0) {
        float dv = dis[v];
        float sc = (MODE == 0) ? dv * dv : dv;
        float4 o4 = make_float4(sc * acc.x, sc * acc.y, sc * acc.z, sc * acc.w);
        if (MODE == 1) {
            float4 bb = ((const float4*)bias)[sub];
            o4.x += bb.x; o4.y += bb.y; o4.z += bb.z; o4.w += bb.w;
        }
        ((float4*)(out + (size_t)v * OUT_CH))[sub] = o4;
    }
}

extern "C" void kernel_launch(void* const* d_in, const int* in_sizes, int n_in,
                              void* d_out, int out_size, void* d_ws, size_t ws_size,
                              hipStream_t stream) {
    const float* x = (const float*)d_in[0];
    const int* ei = (const int*)d_in[1];
    const float* W = (const float*)d_in[2];
    const float* b = (const float*)d_in[3];
    int n = in_sizes[0] / IN_CH;   // 50000
    int E = in_sizes[1] / 2;       // 800000
    const int* row = ei;           // edge_index[0] = source
    const int* col = ei + E;       // edge_index[1] = target

    char* ws = (char*)d_ws;
    size_t o = 0;
    auto alloc = [&](size_t bytes) -> void* {
        void* p = ws + o;
        o += (bytes + 255) & ~(size_t)255;
        return p;
    };
    int*            cnt  = (int*)alloc((size_t)n * 4);
    int*            off  = (int*)alloc((size_t)(n + 1) * 4);
    int*            pos  = (int*)alloc((size_t)n * 4);
    float*          dis  = (float*)alloc((size_t)n * 4);
    unsigned short* eidx = (unsigned short*)alloc((size_t)E * 2);
    float*          zA   = (float*)alloc((size_t)n * OUT_CH * 4);
    float*          zB   = (float*)alloc((size_t)n * OUT_CH * 4);
    int*            bsum = (int*)alloc(1024 * 4);

    int nTiles = (n + 255) / 256;  // 196

    hipMemsetAsync(cnt, 0, (size_t)n * 4, stream);
    count_kernel<<<((E + 3) / 4 + 255) / 256, 256, 0, stream>>>(col, cnt, E);
    partial_kernel<<<nTiles, 256, 0, stream>>>(cnt, bsum, n);
    scansums_kernel<<<1, 256, 0, stream>>>(bsum, nTiles);
    scanwrite_kernel<<<nTiles, 256, 0, stream>>>(cnt, bsum, off, pos, dis, n);
    scatter_kernel<<<768, 256, 0, stream>>>(row, col, pos, eidx, E, n);   // 8 groups x 96 blocks
    gemm_kernel<<<(n + 63) / 64, 256, 0, stream>>>(x, W, dis, zA, n);
    int hopBlocks = (n + 3) / 4;   // wave per node
    hop_kernel<0><<<hopBlocks, 256, 0, stream>>>(zA, zB, eidx, off, dis, nullptr, n);
    hop_kernel<1><<<hopBlocks, 256, 0, stream>>>(zB, (float*)d_out, eidx, off, dis, b, n);
}